// Round 2
// baseline (873.697 us; speedup 1.0000x reference)
//
#include <hip/hip_runtime.h>

#define D_MODEL 2048
#define SEQ     2048
#define NB      2
#define NH      16
#define DH      128
#define MROWS   (NB*SEQ)   /* 4096 */
#define GK      2048       /* K dim of all GEMMs */

typedef __bf16 bf16x8 __attribute__((ext_vector_type(8)));
typedef float  f32x4  __attribute__((ext_vector_type(4)));
typedef unsigned short ushort8 __attribute__((ext_vector_type(8)));

__device__ __forceinline__ unsigned short f2bf(float f) {
  unsigned int u = __float_as_uint(f);
  u += 0x7FFFu + ((u >> 16) & 1u);
  return (unsigned short)(u >> 16);
}

__device__ __forceinline__ void gload16(void* lds, const void* g) {
  __builtin_amdgcn_global_load_lds(
      (__attribute__((address_space(1))) void*)(g),
      (__attribute__((address_space(3))) void*)(lds), 16, 0, 0);
}

/* ---------------- fp32 -> bf16 cast, 8 elems/thread ---------------- */
__global__ __launch_bounds__(256) void cast_f32_bf16(
    const float* __restrict__ in, unsigned short* __restrict__ out) {
  int i = blockIdx.x * 256 + threadIdx.x;
  const float4* p = (const float4*)in;
  float4 a = p[2*i], b = p[2*i+1];
  ushort8 o;
  o[0]=f2bf(a.x); o[1]=f2bf(a.y); o[2]=f2bf(a.z); o[3]=f2bf(a.w);
  o[4]=f2bf(b.x); o[5]=f2bf(b.y); o[6]=f2bf(b.z); o[7]=f2bf(b.w);
  ((ushort8*)out)[i] = o;
}

/* ---------------- GEMM: C[M,N] = A[M,K] * B[N,K]^T + bias ----------------
   m97 structure: 128x128 tile, BK=32, 4 waves, global_load_lds width 16.
   mode 0: bf16 head-major [b,h,s,d] (Q, V)
   mode 2: bf16 K blocked+XOR-swizzled tiles [bh][s/64][img(64x128)]
   mode 1: fp32 [M,N] + bias (out projection)                               */
__global__ __launch_bounds__(256) void gemm_bt(
    const unsigned short* __restrict__ A,
    const unsigned short* __restrict__ B,
    const float* __restrict__ bias,
    unsigned short* __restrict__ outb,
    float* __restrict__ outf,
    int mode)
{
  __shared__ unsigned short As[128*32];
  __shared__ unsigned short Bs[128*32];

  const int tid  = threadIdx.x;
  const int lane = tid & 63;
  const int wid  = tid >> 6;
  const int la   = lane & 15, hi = lane >> 4;
  const int wr   = wid >> 1,  wc = wid & 1;
  const int row0 = blockIdx.y * 128;
  const int col0 = blockIdx.x * 128;

  const unsigned short* Arow = A + (size_t)row0 * GK;
  const unsigned short* Brow = B + (size_t)col0 * GK;

  f32x4 acc[4][4];
  #pragma unroll
  for (int m = 0; m < 4; m++)
    #pragma unroll
    for (int n = 0; n < 4; n++) acc[m][n] = f32x4{0.f,0.f,0.f,0.f};

  for (int k0 = 0; k0 < GK; k0 += 32) {
    #pragma unroll
    for (int i = 0; i < 2; i++) {
      int off = i*4096 + tid*16;        /* byte offset in 8KB tile   */
      int r   = off >> 6;               /* 64B per row (32 bf16)     */
      int ce  = (off & 63) >> 1;        /* element col within K-step */
      gload16((char*)As + off, Arow + (size_t)r*GK + k0 + ce);
      gload16((char*)Bs + off, Brow + (size_t)r*GK + k0 + ce);
    }
    __syncthreads();
    bf16x8 af[4], bfr[4];
    #pragma unroll
    for (int m = 0; m < 4; m++)
      af[m] = *(const bf16x8*)&As[(wr*64 + m*16 + la)*32 + hi*8];
    #pragma unroll
    for (int n = 0; n < 4; n++)
      bfr[n] = *(const bf16x8*)&Bs[(wc*64 + n*16 + la)*32 + hi*8];
    #pragma unroll
    for (int m = 0; m < 4; m++)
      #pragma unroll
      for (int n = 0; n < 4; n++)
        acc[m][n] = __builtin_amdgcn_mfma_f32_16x16x32_bf16(af[m], bfr[n], acc[m][n], 0, 0, 0);
    __syncthreads();
  }

  #pragma unroll
  for (int m = 0; m < 4; m++) {
    #pragma unroll
    for (int n = 0; n < 4; n++) {
      int col = col0 + wc*64 + n*16 + la;
      float bv = bias[col];
      #pragma unroll
      for (int r = 0; r < 4; r++) {
        int row = row0 + wr*64 + m*16 + hi*4 + r;
        float val = acc[m][n][r] + bv;
        if (mode == 0) {
          int b = row >> 11, s = row & (SEQ-1);
          int h = col >> 7,  d = col & (DH-1);
          outb[((size_t)(b*NH + h)*SEQ + s)*DH + d] = f2bf(val);
        } else if (mode == 2) {
          int b = row >> 11, s = row & (SEQ-1);
          int h = col >> 7,  d = col & (DH-1);
          size_t base = ((size_t)(b*NH + h)*SEQ + (size_t)(s >> 6)*64)*DH;
          int boff = (((s & 63) << 8) + (d << 1)) ^ ((s & 7) << 4);
          outb[base + (boff >> 1)] = f2bf(val);
        } else {
          outf[(size_t)row*D_MODEL + col] = val;
        }
      }
    }
  }
}

/* ---------------- V transpose: [bh][s][d] -> blocked+swizzled V^T tiles
   VT[bh][tile=s/64][ img byte (d*128 + kv*2) ^ ((d&7)<<4) ] = V[kv][d]     */
__global__ __launch_bounds__(256) void transpose_v(
    const unsigned short* __restrict__ V, unsigned short* __restrict__ VT)
{
  __shared__ unsigned short T[64*136];
  const int tid  = threadIdx.x;
  const int tile = blockIdx.x, bh = blockIdx.y;
  const unsigned short* vt = V + ((size_t)bh*SEQ + (size_t)tile*64)*DH;
  unsigned short* ot = VT + (size_t)bh*SEQ*DH + (size_t)tile*(64*DH);

  #pragma unroll
  for (int i = 0; i < 4; i++) {
    int chunk = i*256 + tid;
    int r = chunk >> 4, c = (chunk & 15)*8;
    *(ushort8*)&T[r*136 + c] = *(const ushort8*)(vt + (size_t)r*DH + c);
  }
  __syncthreads();
  #pragma unroll
  for (int i = 0; i < 4; i++) {
    int chunk = i*256 + tid;
    int d = chunk & 127, kv8 = (chunk >> 7)*8;
    ushort8 o;
    #pragma unroll
    for (int j = 0; j < 8; j++) o[j] = T[(kv8 + j)*136 + d];
    int boff = ((d << 7) + (kv8 << 1)) ^ ((d & 7) << 4);
    *(ushort8*)((char*)ot + boff) = o;
  }
}

/* ---------------- flash attention fwd ----------------
   grid (16 q-tiles, 32 b*h). 4 waves x 32 q-rows. KV tile 64.
   K and V^T staged via global_load_lds from pre-swizzled tiles;
   all LDS b128 reads XOR-swizzled (byte ^= (row&7)<<4) -> conflict-free. */
__global__ __launch_bounds__(256, 3) void attn_fwd(
    const unsigned short* __restrict__ Q,
    const unsigned short* __restrict__ Kg,
    const unsigned short* __restrict__ VTg,
    unsigned short* __restrict__ O)
{
  __shared__ unsigned short Ks [64*128];
  __shared__ unsigned short VTs[128*64];
  __shared__ unsigned short Ps [4*32*64];

  const int tid  = threadIdx.x;
  const int lane = tid & 63, wid = tid >> 6;
  const int la   = lane & 15, hi = lane >> 4;
  const int bh   = blockIdx.y;
  const int q0   = blockIdx.x * 128;
  const int b    = bh >> 4, h = bh & 15;

  const unsigned short* Qh = Q   + (size_t)bh * SEQ * DH;
  const unsigned short* Kh = Kg  + (size_t)bh * SEQ * DH;
  const unsigned short* Vh = VTg + (size_t)bh * SEQ * DH;

  const int qrow = q0 + wid * 32;

  bf16x8 qf[2][4];
  #pragma unroll
  for (int mi = 0; mi < 2; mi++)
    #pragma unroll
    for (int ks = 0; ks < 4; ks++)
      qf[mi][ks] = *(const bf16x8*)(Qh + (size_t)(qrow + mi*16 + la)*DH + ks*32 + hi*8);

  f32x4 o[2][8];
  float mrun[2][4], lrun[2][4];
  #pragma unroll
  for (int mi = 0; mi < 2; mi++) {
    #pragma unroll
    for (int df = 0; df < 8; df++) o[mi][df] = f32x4{0.f,0.f,0.f,0.f};
    #pragma unroll
    for (int r = 0; r < 4; r++) { mrun[mi][r] = -1e30f; lrun[mi][r] = 0.f; }
  }

  #pragma unroll 1
  for (int kv0 = 0; kv0 < SEQ; kv0 += 64) {
    const char* kt = (const char*)(Kh + (size_t)(kv0 >> 6)*(64*DH));
    const char* vt = (const char*)(Vh + (size_t)(kv0 >> 6)*(64*DH));
    #pragma unroll
    for (int i = 0; i < 4; i++) {
      int off = i*4096 + tid*16;
      gload16((char*)Ks  + off, kt + off);
      gload16((char*)VTs + off, vt + off);
    }
    __syncthreads();

    /* S = Q K^T */
    f32x4 S[2][4];
    #pragma unroll
    for (int mi = 0; mi < 2; mi++)
      #pragma unroll
      for (int n = 0; n < 4; n++) S[mi][n] = f32x4{0.f,0.f,0.f,0.f};
    #pragma unroll
    for (int ks = 0; ks < 4; ks++) {
      bf16x8 kf[4];
      #pragma unroll
      for (int n = 0; n < 4; n++) {
        int boff = (((n*16 + la) << 8) + (ks << 6) + (hi << 4)) ^ ((la & 7) << 4);
        kf[n] = *(const bf16x8*)((const char*)Ks + boff);
      }
      #pragma unroll
      for (int mi = 0; mi < 2; mi++)
        #pragma unroll
        for (int n = 0; n < 4; n++)
          S[mi][n] = __builtin_amdgcn_mfma_f32_16x16x32_bf16(qf[mi][ks], kf[n], S[mi][n], 0, 0, 0);
    }

    const float sc = 0.08838834764831845f; /* 1/sqrt(128) */
    #pragma unroll
    for (int mi = 0; mi < 2; mi++)
      #pragma unroll
      for (int n = 0; n < 4; n++)
        #pragma unroll
        for (int r = 0; r < 4; r++) S[mi][n][r] *= sc;

    /* online softmax; rows live in 16-lane groups */
    #pragma unroll
    for (int mi = 0; mi < 2; mi++) {
      #pragma unroll
      for (int r = 0; r < 4; r++) {
        float pm = fmaxf(fmaxf(S[mi][0][r], S[mi][1][r]), fmaxf(S[mi][2][r], S[mi][3][r]));
        pm = fmaxf(pm, __shfl_xor(pm, 1));
        pm = fmaxf(pm, __shfl_xor(pm, 2));
        pm = fmaxf(pm, __shfl_xor(pm, 4));
        pm = fmaxf(pm, __shfl_xor(pm, 8));
        float mn = fmaxf(mrun[mi][r], pm);
        float alpha = __expf(mrun[mi][r] - mn);
        mrun[mi][r] = mn;
        float rs = 0.f;
        #pragma unroll
        for (int n = 0; n < 4; n++) {
          float p = __expf(S[mi][n][r] - mn);
          S[mi][n][r] = p;
          rs += p;
        }
        rs += __shfl_xor(rs, 1);
        rs += __shfl_xor(rs, 2);
        rs += __shfl_xor(rs, 4);
        rs += __shfl_xor(rs, 8);
        lrun[mi][r] = lrun[mi][r]*alpha + rs;
        #pragma unroll
        for (int df = 0; df < 8; df++) o[mi][df][r] *= alpha;
      }
    }

    /* P -> per-wave LDS (XOR-swizzled rows), read back as A-fragments */
    const int pb = wid << 12;   /* byte base */
    #pragma unroll
    for (int mi = 0; mi < 2; mi++)
      #pragma unroll
      for (int n = 0; n < 4; n++)
        #pragma unroll
        for (int r = 0; r < 4; r++) {
          int prow = mi*16 + hi*4 + r;
          int boff = ((prow << 7) + ((n*16 + la) << 1)) ^ ((prow & 7) << 4);
          *(unsigned short*)((char*)Ps + pb + boff) = f2bf(S[mi][n][r]);
        }

    #pragma unroll
    for (int ks2 = 0; ks2 < 2; ks2++) {
      bf16x8 pf[2];
      #pragma unroll
      for (int mi = 0; mi < 2; mi++) {
        int arow = mi*16 + la;
        int boff = ((arow << 7) + (ks2 << 6) + (hi << 4)) ^ ((arow & 7) << 4);
        pf[mi] = *(const bf16x8*)((const char*)Ps + pb + boff);
      }
      #pragma unroll
      for (int df = 0; df < 8; df++) {
        int vrow = df*16 + la;
        int boff = ((vrow << 7) + (ks2 << 6) + (hi << 4)) ^ ((vrow & 7) << 4);
        bf16x8 vf = *(const bf16x8*)((const char*)VTs + boff);
        #pragma unroll
        for (int mi = 0; mi < 2; mi++)
          o[mi][df] = __builtin_amdgcn_mfma_f32_16x16x32_bf16(pf[mi], vf, o[mi][df], 0, 0, 0);
      }
    }
    __syncthreads();
  }

  /* epilogue: O[b][s][h*128+d] bf16 */
  unsigned short* Ob = O + (size_t)b * SEQ * D_MODEL + h * DH;
  #pragma unroll
  for (int mi = 0; mi < 2; mi++)
    #pragma unroll
    for (int df = 0; df < 8; df++)
      #pragma unroll
      for (int r = 0; r < 4; r++) {
        int srow = qrow + mi*16 + hi*4 + r;
        float val = o[mi][df][r] / lrun[mi][r];
        Ob[(size_t)srow * D_MODEL + df*16 + la] = f2bf(val);
      }
}

/* ---------------- launcher ---------------- */
extern "C" void kernel_launch(void* const* d_in, const int* in_sizes, int n_in,
                              void* d_out, int out_size, void* d_ws, size_t ws_size,
                              hipStream_t stream) {
  const float* x  = (const float*)d_in[0];
  const float* wq = (const float*)d_in[1];
  const float* bq = (const float*)d_in[2];
  const float* wk = (const float*)d_in[3];
  const float* bk = (const float*)d_in[4];
  const float* wv = (const float*)d_in[5];
  const float* bv = (const float*)d_in[6];
  const float* wo = (const float*)d_in[7];
  const float* bo = (const float*)d_in[8];
  float* out = (float*)d_out;

  const size_t X = (size_t)MROWS * D_MODEL;   /* 8388608  */
  const size_t W = (size_t)D_MODEL * D_MODEL; /* 4194304  */

  unsigned short* ws  = (unsigned short*)d_ws;
  unsigned short* xb  = ws;
  unsigned short* wqb = xb  + X;
  unsigned short* wkb = wqb + W;
  unsigned short* wvb = wkb + W;
  unsigned short* wob = wvb + W;
  unsigned short* qb  = wob + W;
  unsigned short* kb  = qb  + X;
  unsigned short* vb  = kb  + X;
  unsigned short* ab  = vb  + X;
  unsigned short* vtg = xb;   /* alias: xb dead after QKV GEMMs */

  cast_f32_bf16<<<dim3((unsigned)(X/2048)), 256, 0, stream>>>(x,  xb);
  cast_f32_bf16<<<dim3((unsigned)(W/2048)), 256, 0, stream>>>(wq, wqb);
  cast_f32_bf16<<<dim3((unsigned)(W/2048)), 256, 0, stream>>>(wk, wkb);
  cast_f32_bf16<<<dim3((unsigned)(W/2048)), 256, 0, stream>>>(wv, wvb);
  cast_f32_bf16<<<dim3((unsigned)(W/2048)), 256, 0, stream>>>(wo, wob);

  dim3 ggrid(D_MODEL/128, MROWS/128);  /* 16 x 32 */
  gemm_bt<<<ggrid, 256, 0, stream>>>(xb, wqb, bq, qb, nullptr, 0);
  gemm_bt<<<ggrid, 256, 0, stream>>>(xb, wkb, bk, kb, nullptr, 2);
  gemm_bt<<<ggrid, 256, 0, stream>>>(xb, wvb, bv, vb, nullptr, 0);

  transpose_v<<<dim3(SEQ/64, NB*NH), 256, 0, stream>>>(vb, vtg);

  attn_fwd<<<dim3(SEQ/128, NB*NH), 256, 0, stream>>>(qb, kb, vtg, ab);

  gemm_bt<<<ggrid, 256, 0, stream>>>(ab, wob, bo, nullptr, out, 1);
}

// Round 3
// 387.763 us; speedup vs baseline: 2.2532x; 2.2532x over previous
//
#include <hip/hip_runtime.h>

#define D_MODEL 2048
#define SEQ     2048
#define NB      2
#define NH      16
#define DH      128
#define MROWS   (NB*SEQ)   /* 4096 */
#define GK      2048       /* K dim of all GEMMs */

typedef __bf16 bf16x8 __attribute__((ext_vector_type(8)));
typedef float  f32x4  __attribute__((ext_vector_type(4)));
typedef unsigned short ushort8 __attribute__((ext_vector_type(8)));

__device__ __forceinline__ unsigned short f2bf(float f) {
  unsigned int u = __float_as_uint(f);
  u += 0x7FFFu + ((u >> 16) & 1u);
  return (unsigned short)(u >> 16);
}

__device__ __forceinline__ void gload16(void* lds, const void* g) {
  __builtin_amdgcn_global_load_lds(
      (__attribute__((address_space(1))) void*)(g),
      (__attribute__((address_space(3))) void*)(lds), 16, 0, 0);
}

/* ---------------- fp32 -> bf16 cast, 8 elems/thread ---------------- */
__global__ __launch_bounds__(256) void cast_f32_bf16(
    const float* __restrict__ in, unsigned short* __restrict__ out) {
  int i = blockIdx.x * 256 + threadIdx.x;
  const float4* p = (const float4*)in;
  float4 a = p[2*i], b = p[2*i+1];
  ushort8 o;
  o[0]=f2bf(a.x); o[1]=f2bf(a.y); o[2]=f2bf(a.z); o[3]=f2bf(a.w);
  o[4]=f2bf(b.x); o[5]=f2bf(b.y); o[6]=f2bf(b.z); o[7]=f2bf(b.w);
  ((ushort8*)out)[i] = o;
}

/* ---------------- GEMM: C[M,N] = A[M,K] * B[N,K]^T + bias ----------------
   m97 structure: 128x128 tile, BK=32, 4 waves, global_load_lds width 16.
   mode 0: bf16 head-major [b,h,s,d] (Q, V)
   mode 2: bf16 K blocked+XOR-swizzled tiles [bh][s/64][img(64x128)]
   mode 1: fp32 [M,N] + bias (out projection)                               */
__global__ __launch_bounds__(256) void gemm_bt(
    const unsigned short* __restrict__ A,
    const unsigned short* __restrict__ B,
    const float* __restrict__ bias,
    unsigned short* __restrict__ outb,
    float* __restrict__ outf,
    int mode)
{
  __shared__ unsigned short As[128*32];
  __shared__ unsigned short Bs[128*32];

  const int tid  = threadIdx.x;
  const int lane = tid & 63;
  const int wid  = tid >> 6;
  const int la   = lane & 15, hi = lane >> 4;
  const int wr   = wid >> 1,  wc = wid & 1;
  const int row0 = blockIdx.y * 128;
  const int col0 = blockIdx.x * 128;

  const unsigned short* Arow = A + (size_t)row0 * GK;
  const unsigned short* Brow = B + (size_t)col0 * GK;

  f32x4 acc[4][4];
  #pragma unroll
  for (int m = 0; m < 4; m++)
    #pragma unroll
    for (int n = 0; n < 4; n++) acc[m][n] = f32x4{0.f,0.f,0.f,0.f};

  for (int k0 = 0; k0 < GK; k0 += 32) {
    #pragma unroll
    for (int i = 0; i < 2; i++) {
      int off = i*4096 + tid*16;        /* byte offset in 8KB tile   */
      int r   = off >> 6;               /* 64B per row (32 bf16)     */
      int ce  = (off & 63) >> 1;        /* element col within K-step */
      gload16((char*)As + off, Arow + (size_t)r*GK + k0 + ce);
      gload16((char*)Bs + off, Brow + (size_t)r*GK + k0 + ce);
    }
    __syncthreads();
    bf16x8 af[4], bfr[4];
    #pragma unroll
    for (int m = 0; m < 4; m++)
      af[m] = *(const bf16x8*)&As[(wr*64 + m*16 + la)*32 + hi*8];
    #pragma unroll
    for (int n = 0; n < 4; n++)
      bfr[n] = *(const bf16x8*)&Bs[(wc*64 + n*16 + la)*32 + hi*8];
    #pragma unroll
    for (int m = 0; m < 4; m++)
      #pragma unroll
      for (int n = 0; n < 4; n++)
        acc[m][n] = __builtin_amdgcn_mfma_f32_16x16x32_bf16(af[m], bfr[n], acc[m][n], 0, 0, 0);
    __syncthreads();
  }

  #pragma unroll
  for (int m = 0; m < 4; m++) {
    #pragma unroll
    for (int n = 0; n < 4; n++) {
      int col = col0 + wc*64 + n*16 + la;
      float bv = bias[col];
      #pragma unroll
      for (int r = 0; r < 4; r++) {
        int row = row0 + wr*64 + m*16 + hi*4 + r;
        float val = acc[m][n][r] + bv;
        if (mode == 0) {
          int b = row >> 11, s = row & (SEQ-1);
          int h = col >> 7,  d = col & (DH-1);
          outb[((size_t)(b*NH + h)*SEQ + s)*DH + d] = f2bf(val);
        } else if (mode == 2) {
          int b = row >> 11, s = row & (SEQ-1);
          int h = col >> 7,  d = col & (DH-1);
          size_t base = ((size_t)(b*NH + h)*SEQ + (size_t)(s >> 6)*64)*DH;
          int boff = (((s & 63) << 8) + (d << 1)) ^ ((s & 7) << 4);
          outb[base + (boff >> 1)] = f2bf(val);
        } else {
          outf[(size_t)row*D_MODEL + col] = val;
        }
      }
    }
  }
}

/* ---------------- V transpose: [bh][s][d] -> blocked+swizzled V^T tiles
   VT[bh][tile=s/64][ img byte (d*128 + kv*2) ^ ((d&7)<<4) ] = V[kv][d]     */
__global__ __launch_bounds__(256) void transpose_v(
    const unsigned short* __restrict__ V, unsigned short* __restrict__ VT)
{
  __shared__ unsigned short T[64*136];
  const int tid  = threadIdx.x;
  const int tile = blockIdx.x, bh = blockIdx.y;
  const unsigned short* vt = V + ((size_t)bh*SEQ + (size_t)tile*64)*DH;
  unsigned short* ot = VT + (size_t)bh*SEQ*DH + (size_t)tile*(64*DH);

  #pragma unroll
  for (int i = 0; i < 4; i++) {
    int chunk = i*256 + tid;
    int r = chunk >> 4, c = (chunk & 15)*8;
    *(ushort8*)&T[r*136 + c] = *(const ushort8*)(vt + (size_t)r*DH + c);
  }
  __syncthreads();
  #pragma unroll
  for (int i = 0; i < 4; i++) {
    int chunk = i*256 + tid;
    int d = chunk & 127, kv8 = (chunk >> 7)*8;
    ushort8 o;
    #pragma unroll
    for (int j = 0; j < 8; j++) o[j] = T[(kv8 + j)*136 + d];
    int boff = ((d << 7) + (kv8 << 1)) ^ ((d & 7) << 4);
    *(ushort8*)((char*)ot + boff) = o;
  }
}

/* ---------------- flash attention fwd ----------------
   512 blocks, XCD-swizzled so each XCD owns 4 bh (K+V working set = 4MB = L2).
   4 waves x 32 q-rows, KV tile 64, double-buffered K/V LDS (80KB), 2-phase
   pipeline: issue next-tile global_load_lds before current-tile compute,
   one vmcnt-drain barrier per tile. All LDS reads XOR-swizzled.            */
__global__ __launch_bounds__(256, 2) void attn_fwd(
    const unsigned short* __restrict__ Q,
    const unsigned short* __restrict__ Kg,
    const unsigned short* __restrict__ VTg,
    unsigned short* __restrict__ O)
{
  __shared__ unsigned short Ks [2][64*128];
  __shared__ unsigned short VTs[2][128*64];
  __shared__ unsigned short Ps [4*32*64];

  const int tid  = threadIdx.x;
  const int lane = tid & 63, wid = tid >> 6;
  const int la   = lane & 15, hi = lane >> 4;
  const int swz  = ((int)(blockIdx.x & 7) << 6) + ((int)blockIdx.x >> 3);
  const int bh   = swz >> 4;
  const int q0   = (swz & 15) << 7;
  const int b    = bh >> 4, h = bh & 15;

  const unsigned short* Qh = Q   + (size_t)bh * SEQ * DH;
  const unsigned short* Kh = Kg  + (size_t)bh * SEQ * DH;
  const unsigned short* Vh = VTg + (size_t)bh * SEQ * DH;

  const int qrow = q0 + wid * 32;

  bf16x8 qf[2][4];
  #pragma unroll
  for (int mi = 0; mi < 2; mi++)
    #pragma unroll
    for (int ks = 0; ks < 4; ks++)
      qf[mi][ks] = *(const bf16x8*)(Qh + (size_t)(qrow + mi*16 + la)*DH + ks*32 + hi*8);

  f32x4 o[2][8];
  float mrun[2][4], lrun[2][4];
  #pragma unroll
  for (int mi = 0; mi < 2; mi++) {
    #pragma unroll
    for (int df = 0; df < 8; df++) o[mi][df] = f32x4{0.f,0.f,0.f,0.f};
    #pragma unroll
    for (int r = 0; r < 4; r++) { mrun[mi][r] = -1e30f; lrun[mi][r] = 0.f; }
  }

  /* prologue: stage tile 0 -> buffer 0 */
  #pragma unroll
  for (int i = 0; i < 4; i++) {
    int off = i*4096 + tid*16;
    gload16((char*)Ks[0]  + off, (const char*)Kh + off);
    gload16((char*)VTs[0] + off, (const char*)Vh + off);
  }
  __syncthreads();

  #pragma unroll 1
  for (int t = 0; t < SEQ/64; ++t) {
    const int cur = t & 1;

    /* issue next-tile stage first (overlaps with this tile's compute) */
    if (t + 1 < SEQ/64) {
      const char* kt = (const char*)(Kh + (size_t)(t+1)*(64*DH));
      const char* vt = (const char*)(Vh + (size_t)(t+1)*(64*DH));
      #pragma unroll
      for (int i = 0; i < 4; i++) {
        int off = i*4096 + tid*16;
        gload16((char*)Ks[cur^1]  + off, kt + off);
        gload16((char*)VTs[cur^1] + off, vt + off);
      }
    }

    /* S = Q K^T */
    f32x4 S[2][4];
    #pragma unroll
    for (int mi = 0; mi < 2; mi++)
      #pragma unroll
      for (int n = 0; n < 4; n++) S[mi][n] = f32x4{0.f,0.f,0.f,0.f};
    #pragma unroll
    for (int ks = 0; ks < 4; ks++) {
      bf16x8 kf[4];
      #pragma unroll
      for (int n = 0; n < 4; n++) {
        int boff = (((n*16 + la) << 8) + (ks << 6) + (hi << 4)) ^ ((la & 7) << 4);
        kf[n] = *(const bf16x8*)((const char*)Ks[cur] + boff);
      }
      #pragma unroll
      for (int mi = 0; mi < 2; mi++)
        #pragma unroll
        for (int n = 0; n < 4; n++)
          S[mi][n] = __builtin_amdgcn_mfma_f32_16x16x32_bf16(qf[mi][ks], kf[n], S[mi][n], 0, 0, 0);
    }

    const float sc = 0.08838834764831845f; /* 1/sqrt(128) */
    #pragma unroll
    for (int mi = 0; mi < 2; mi++)
      #pragma unroll
      for (int n = 0; n < 4; n++)
        #pragma unroll
        for (int r = 0; r < 4; r++) S[mi][n][r] *= sc;

    /* online softmax; rows live in 16-lane groups */
    #pragma unroll
    for (int mi = 0; mi < 2; mi++) {
      #pragma unroll
      for (int r = 0; r < 4; r++) {
        float pm = fmaxf(fmaxf(S[mi][0][r], S[mi][1][r]), fmaxf(S[mi][2][r], S[mi][3][r]));
        pm = fmaxf(pm, __shfl_xor(pm, 1));
        pm = fmaxf(pm, __shfl_xor(pm, 2));
        pm = fmaxf(pm, __shfl_xor(pm, 4));
        pm = fmaxf(pm, __shfl_xor(pm, 8));
        float mn = fmaxf(mrun[mi][r], pm);
        float alpha = __expf(mrun[mi][r] - mn);
        mrun[mi][r] = mn;
        float rs = 0.f;
        #pragma unroll
        for (int n = 0; n < 4; n++) {
          float p = __expf(S[mi][n][r] - mn);
          S[mi][n][r] = p;
          rs += p;
        }
        rs += __shfl_xor(rs, 1);
        rs += __shfl_xor(rs, 2);
        rs += __shfl_xor(rs, 4);
        rs += __shfl_xor(rs, 8);
        lrun[mi][r] = lrun[mi][r]*alpha + rs;
        #pragma unroll
        for (int df = 0; df < 8; df++) o[mi][df][r] *= alpha;
      }
    }

    /* P -> per-wave LDS (XOR-swizzled rows), read back as A-fragments */
    const int pb = wid << 12;   /* byte base */
    #pragma unroll
    for (int mi = 0; mi < 2; mi++)
      #pragma unroll
      for (int n = 0; n < 4; n++)
        #pragma unroll
        for (int r = 0; r < 4; r++) {
          int prow = mi*16 + hi*4 + r;
          int boff = ((prow << 7) + ((n*16 + la) << 1)) ^ ((prow & 7) << 4);
          *(unsigned short*)((char*)Ps + pb + boff) = f2bf(S[mi][n][r]);
        }

    #pragma unroll
    for (int ks2 = 0; ks2 < 2; ks2++) {
      bf16x8 pf[2];
      #pragma unroll
      for (int mi = 0; mi < 2; mi++) {
        int arow = mi*16 + la;
        int boff = ((arow << 7) + (ks2 << 6) + (hi << 4)) ^ ((arow & 7) << 4);
        pf[mi] = *(const bf16x8*)((const char*)Ps + pb + boff);
      }
      #pragma unroll
      for (int df = 0; df < 8; df++) {
        int vrow = df*16 + la;
        int boff = ((vrow << 7) + (ks2 << 6) + (hi << 4)) ^ ((vrow & 7) << 4);
        bf16x8 vf = *(const bf16x8*)((const char*)VTs[cur] + boff);
        #pragma unroll
        for (int mi = 0; mi < 2; mi++)
          o[mi][df] = __builtin_amdgcn_mfma_f32_16x16x32_bf16(pf[mi], vf, o[mi][df], 0, 0, 0);
      }
    }
    __syncthreads();   /* drains vmcnt (next tile staged) + lgkm; guards buf reuse */
  }

  /* epilogue: O[b][s][h*128+d] bf16 */
  unsigned short* Ob = O + (size_t)b * SEQ * D_MODEL + h * DH;
  #pragma unroll
  for (int mi = 0; mi < 2; mi++)
    #pragma unroll
    for (int df = 0; df < 8; df++)
      #pragma unroll
      for (int r = 0; r < 4; r++) {
        int srow = qrow + mi*16 + hi*4 + r;
        float val = o[mi][df][r] / lrun[mi][r];
        Ob[(size_t)srow * D_MODEL + df*16 + la] = f2bf(val);
      }
}

/* ---------------- launcher ---------------- */
extern "C" void kernel_launch(void* const* d_in, const int* in_sizes, int n_in,
                              void* d_out, int out_size, void* d_ws, size_t ws_size,
                              hipStream_t stream) {
  const float* x  = (const float*)d_in[0];
  const float* wq = (const float*)d_in[1];
  const float* bq = (const float*)d_in[2];
  const float* wk = (const float*)d_in[3];
  const float* bk = (const float*)d_in[4];
  const float* wv = (const float*)d_in[5];
  const float* bv = (const float*)d_in[6];
  const float* wo = (const float*)d_in[7];
  const float* bo = (const float*)d_in[8];
  float* out = (float*)d_out;

  const size_t X = (size_t)MROWS * D_MODEL;   /* 8388608  */
  const size_t W = (size_t)D_MODEL * D_MODEL; /* 4194304  */

  unsigned short* ws  = (unsigned short*)d_ws;
  unsigned short* xb  = ws;
  unsigned short* wqb = xb  + X;
  unsigned short* wkb = wqb + W;
  unsigned short* wvb = wkb + W;
  unsigned short* wob = wvb + W;
  unsigned short* qb  = wob + W;
  unsigned short* kb  = qb  + X;
  unsigned short* vb  = kb  + X;
  unsigned short* ab  = vb  + X;
  unsigned short* vtg = xb;   /* alias: xb dead after QKV GEMMs */

  cast_f32_bf16<<<dim3((unsigned)(X/2048)), 256, 0, stream>>>(x,  xb);
  cast_f32_bf16<<<dim3((unsigned)(W/2048)), 256, 0, stream>>>(wq, wqb);
  cast_f32_bf16<<<dim3((unsigned)(W/2048)), 256, 0, stream>>>(wk, wkb);
  cast_f32_bf16<<<dim3((unsigned)(W/2048)), 256, 0, stream>>>(wv, wvb);
  cast_f32_bf16<<<dim3((unsigned)(W/2048)), 256, 0, stream>>>(wo, wob);

  dim3 ggrid(D_MODEL/128, MROWS/128);  /* 16 x 32 */
  gemm_bt<<<ggrid, 256, 0, stream>>>(xb, wqb, bq, qb, nullptr, 0);
  gemm_bt<<<ggrid, 256, 0, stream>>>(xb, wkb, bk, kb, nullptr, 2);
  gemm_bt<<<ggrid, 256, 0, stream>>>(xb, wvb, bv, vb, nullptr, 0);

  transpose_v<<<dim3(SEQ/64, NB*NH), 256, 0, stream>>>(vb, vtg);

  attn_fwd<<<dim3(512), 256, 0, stream>>>(qb, kb, vtg, ab);

  gemm_bt<<<ggrid, 256, 0, stream>>>(ab, wob, bo, nullptr, out, 1);
}

// Round 4
// 345.334 us; speedup vs baseline: 2.5300x; 1.1229x over previous
//
#include <hip/hip_runtime.h>

#define D_MODEL 2048
#define SEQ     2048
#define NB      2
#define NH      16
#define DH      128
#define MROWS   (NB*SEQ)   /* 4096 */
#define GK      2048       /* K dim of all GEMMs */

typedef __bf16 bf16x8 __attribute__((ext_vector_type(8)));
typedef float  f32x4  __attribute__((ext_vector_type(4)));
typedef unsigned short ushort8 __attribute__((ext_vector_type(8)));
typedef unsigned int   u32x4   __attribute__((ext_vector_type(4)));

__device__ __forceinline__ unsigned short f2bf(float f) {
  unsigned int u = __float_as_uint(f);
  u += 0x7FFFu + ((u >> 16) & 1u);
  return (unsigned short)(u >> 16);
}

__device__ __forceinline__ unsigned int cvtpk_bf16(float lo, float hi) {
  unsigned int r;
  asm("v_cvt_pk_bf16_f32 %0, %1, %2" : "=v"(r) : "v"(lo), "v"(hi));
  return r;
}

__device__ __forceinline__ void gload16(void* lds, const void* g) {
  __builtin_amdgcn_global_load_lds(
      (__attribute__((address_space(1))) void*)(g),
      (__attribute__((address_space(3))) void*)(lds), 16, 0, 0);
}

/* ---------------- fp32 -> bf16 cast, 8 elems/thread ---------------- */
__global__ __launch_bounds__(256) void cast_f32_bf16(
    const float* __restrict__ in, unsigned short* __restrict__ out) {
  int i = blockIdx.x * 256 + threadIdx.x;
  const float4* p = (const float4*)in;
  float4 a = p[2*i], b = p[2*i+1];
  ushort8 o;
  o[0]=f2bf(a.x); o[1]=f2bf(a.y); o[2]=f2bf(a.z); o[3]=f2bf(a.w);
  o[4]=f2bf(b.x); o[5]=f2bf(b.y); o[6]=f2bf(b.z); o[7]=f2bf(b.w);
  ((ushort8*)out)[i] = o;
}

/* ---------------- GEMM: C[M,N] = A[M,K] * B[N,K]^T + bias ----------------
   m97 structure: 128x128 tile, BK=32, 4 waves, global_load_lds width 16.
   mode 0: bf16 head-major [b,h,s,d] (Q, V)
   mode 2: bf16 K blocked+XOR-swizzled tiles [bh][s/64][img(64x128)]
   mode 1: fp32 [M,N] + bias (out projection)                               */
__global__ __launch_bounds__(256) void gemm_bt(
    const unsigned short* __restrict__ A,
    const unsigned short* __restrict__ B,
    const float* __restrict__ bias,
    unsigned short* __restrict__ outb,
    float* __restrict__ outf,
    int mode)
{
  __shared__ unsigned short As[128*32];
  __shared__ unsigned short Bs[128*32];

  const int tid  = threadIdx.x;
  const int lane = tid & 63;
  const int wid  = tid >> 6;
  const int la   = lane & 15, hi = lane >> 4;
  const int wr   = wid >> 1,  wc = wid & 1;
  const int row0 = blockIdx.y * 128;
  const int col0 = blockIdx.x * 128;

  const unsigned short* Arow = A + (size_t)row0 * GK;
  const unsigned short* Brow = B + (size_t)col0 * GK;

  f32x4 acc[4][4];
  #pragma unroll
  for (int m = 0; m < 4; m++)
    #pragma unroll
    for (int n = 0; n < 4; n++) acc[m][n] = f32x4{0.f,0.f,0.f,0.f};

  for (int k0 = 0; k0 < GK; k0 += 32) {
    #pragma unroll
    for (int i = 0; i < 2; i++) {
      int off = i*4096 + tid*16;        /* byte offset in 8KB tile   */
      int r   = off >> 6;               /* 64B per row (32 bf16)     */
      int ce  = (off & 63) >> 1;        /* element col within K-step */
      gload16((char*)As + off, Arow + (size_t)r*GK + k0 + ce);
      gload16((char*)Bs + off, Brow + (size_t)r*GK + k0 + ce);
    }
    __syncthreads();
    bf16x8 af[4], bfr[4];
    #pragma unroll
    for (int m = 0; m < 4; m++)
      af[m] = *(const bf16x8*)&As[(wr*64 + m*16 + la)*32 + hi*8];
    #pragma unroll
    for (int n = 0; n < 4; n++)
      bfr[n] = *(const bf16x8*)&Bs[(wc*64 + n*16 + la)*32 + hi*8];
    #pragma unroll
    for (int m = 0; m < 4; m++)
      #pragma unroll
      for (int n = 0; n < 4; n++)
        acc[m][n] = __builtin_amdgcn_mfma_f32_16x16x32_bf16(af[m], bfr[n], acc[m][n], 0, 0, 0);
    __syncthreads();
  }

  #pragma unroll
  for (int m = 0; m < 4; m++) {
    #pragma unroll
    for (int n = 0; n < 4; n++) {
      int col = col0 + wc*64 + n*16 + la;
      float bv = bias[col];
      #pragma unroll
      for (int r = 0; r < 4; r++) {
        int row = row0 + wr*64 + m*16 + hi*4 + r;
        float val = acc[m][n][r] + bv;
        if (mode == 0) {
          int b = row >> 11, s = row & (SEQ-1);
          int h = col >> 7,  d = col & (DH-1);
          outb[((size_t)(b*NH + h)*SEQ + s)*DH + d] = f2bf(val);
        } else if (mode == 2) {
          int b = row >> 11, s = row & (SEQ-1);
          int h = col >> 7,  d = col & (DH-1);
          size_t base = ((size_t)(b*NH + h)*SEQ + (size_t)(s >> 6)*64)*DH;
          int boff = (((s & 63) << 8) + (d << 1)) ^ ((s & 7) << 4);
          outb[base + (boff >> 1)] = f2bf(val);
        } else {
          outf[(size_t)row*D_MODEL + col] = val;
        }
      }
    }
  }
}

/* ---------------- V transpose: [bh][s][d] -> blocked+swizzled V^T tiles
   VT[bh][tile=s/64][ img byte (d*128 + kv*2) ^ ((d&7)<<4) ] = V[kv][d]     */
__global__ __launch_bounds__(256) void transpose_v(
    const unsigned short* __restrict__ V, unsigned short* __restrict__ VT)
{
  __shared__ unsigned short T[64*136];
  const int tid  = threadIdx.x;
  const int tile = blockIdx.x, bh = blockIdx.y;
  const unsigned short* vt = V + ((size_t)bh*SEQ + (size_t)tile*64)*DH;
  unsigned short* ot = VT + (size_t)bh*SEQ*DH + (size_t)tile*(64*DH);

  #pragma unroll
  for (int i = 0; i < 4; i++) {
    int chunk = i*256 + tid;
    int r = chunk >> 4, c = (chunk & 15)*8;
    *(ushort8*)&T[r*136 + c] = *(const ushort8*)(vt + (size_t)r*DH + c);
  }
  __syncthreads();
  #pragma unroll
  for (int i = 0; i < 4; i++) {
    int chunk = i*256 + tid;
    int d = chunk & 127, kv8 = (chunk >> 7)*8;
    ushort8 o;
    #pragma unroll
    for (int j = 0; j < 8; j++) o[j] = T[(kv8 + j)*136 + d];
    int boff = ((d << 7) + (kv8 << 1)) ^ ((d & 7) << 4);
    *(ushort8*)((char*)ot + boff) = o;
  }
}

/* ---------------- flash attention fwd ----------------
   512 blocks XCD-swizzled (4 bh per XCD -> K/V L2-resident).
   4 waves x 32 q-rows, KV tile 64, double-buffered K/V LDS (64KB).
   Swapped QK^T (S^T = mfma(K,Q)) -> softmax fully in-register
   (lane owns one q-row per q-frag), P assembled to PV A-frags via
   cvt_pk_bf16 + shfl (no P LDS round-trip, no mid-tile barrier).           */
__global__ __launch_bounds__(256, 2) void attn_fwd(
    const unsigned short* __restrict__ Q,
    const unsigned short* __restrict__ Kg,
    const unsigned short* __restrict__ VTg,
    unsigned short* __restrict__ O)
{
  __shared__ unsigned short Ks [2][64*128];
  __shared__ unsigned short VTs[2][128*64];

  const int tid  = threadIdx.x;
  const int lane = tid & 63, wid = tid >> 6;
  const int la   = lane & 15, hi = lane >> 4;
  const int swz  = ((int)(blockIdx.x & 7) << 6) + ((int)blockIdx.x >> 3);
  const int bh   = swz >> 4;
  const int q0   = (swz & 15) << 7;
  const int b    = bh >> 4, h = bh & 15;

  const unsigned short* Qh = Q   + (size_t)bh * SEQ * DH;
  const unsigned short* Kh = Kg  + (size_t)bh * SEQ * DH;
  const unsigned short* Vh = VTg + (size_t)bh * SEQ * DH;

  const int qrow = q0 + wid * 32;

  /* Q fragments: lane holds Q[qrow + qi*16 + la][hi*8.. + ks*32] (B-frag) */
  bf16x8 qf[2][4];
  #pragma unroll
  for (int qi = 0; qi < 2; qi++)
    #pragma unroll
    for (int ks = 0; ks < 4; ks++)
      qf[qi][ks] = *(const bf16x8*)(Qh + (size_t)(qrow + qi*16 + la)*DH + ks*32 + hi*8);

  f32x4 o[2][8];           /* o[qi][df]: O[qrow+qi*16+hi*4+r][df*16+la] */
  float mrun[2], lrun[2];  /* per-lane: row q = qrow + qi*16 + la        */
  #pragma unroll
  for (int qi = 0; qi < 2; qi++) {
    #pragma unroll
    for (int df = 0; df < 8; df++) o[qi][df] = f32x4{0.f,0.f,0.f,0.f};
    mrun[qi] = -1e30f; lrun[qi] = 0.f;
  }

  /* prologue: stage tile 0 -> buffer 0 */
  #pragma unroll
  for (int i = 0; i < 4; i++) {
    int off = i*4096 + tid*16;
    gload16((char*)Ks[0]  + off, (const char*)Kh + off);
    gload16((char*)VTs[0] + off, (const char*)Vh + off);
  }
  __syncthreads();

  const float sc = 0.08838834764831845f; /* 1/sqrt(128) */

  #pragma unroll 1
  for (int t = 0; t < SEQ/64; ++t) {
    const int cur = t & 1;

    /* issue next-tile stage first (overlaps with this tile's compute) */
    if (t + 1 < SEQ/64) {
      const char* kt = (const char*)(Kh + (size_t)(t+1)*(64*DH));
      const char* vt = (const char*)(Vh + (size_t)(t+1)*(64*DH));
      #pragma unroll
      for (int i = 0; i < 4; i++) {
        int off = i*4096 + tid*16;
        gload16((char*)Ks[cur^1]  + off, kt + off);
        gload16((char*)VTs[cur^1] + off, vt + off);
      }
    }

    /* S^T[kv][q] = K Q^T : S[mf][qi], kv = mf*16+hi*4+r, q = qi*16+la */
    f32x4 S[4][2];
    #pragma unroll
    for (int mf = 0; mf < 4; mf++)
      #pragma unroll
      for (int qi = 0; qi < 2; qi++) S[mf][qi] = f32x4{0.f,0.f,0.f,0.f};
    #pragma unroll
    for (int ks = 0; ks < 4; ks++) {
      bf16x8 kf[4];
      #pragma unroll
      for (int mf = 0; mf < 4; mf++) {
        int boff = (((mf*16 + la) << 8) + (ks << 6) + (hi << 4)) ^ ((la & 7) << 4);
        kf[mf] = *(const bf16x8*)((const char*)Ks[cur] + boff);
      }
      #pragma unroll
      for (int mf = 0; mf < 4; mf++)
        #pragma unroll
        for (int qi = 0; qi < 2; qi++)
          S[mf][qi] = __builtin_amdgcn_mfma_f32_16x16x32_bf16(kf[mf], qf[qi][ks], S[mf][qi], 0, 0, 0);
    }

    /* in-register online softmax + P fragment assembly */
    unsigned int pf[2][2][4];  /* [qi][ks2][word] -> PV A-frag */
    #pragma unroll
    for (int qi = 0; qi < 2; qi++) {
      float pm = S[0][qi][0];
      #pragma unroll
      for (int mf = 0; mf < 4; mf++)
        #pragma unroll
        for (int r = 0; r < 4; r++) pm = fmaxf(pm, S[mf][qi][r]);
      pm = fmaxf(pm, __shfl_xor(pm, 16));
      pm = fmaxf(pm, __shfl_xor(pm, 32));
      pm *= sc;
      float mn    = fmaxf(mrun[qi], pm);
      float alpha = __expf(mrun[qi] - mn);
      mrun[qi] = mn;

      float p[4][4]; float rs = 0.f;
      #pragma unroll
      for (int mf = 0; mf < 4; mf++)
        #pragma unroll
        for (int r = 0; r < 4; r++) {
          float e = __expf(fmaf(S[mf][qi][r], sc, -mn));
          p[mf][r] = e; rs += e;
        }
      rs += __shfl_xor(rs, 16);
      rs += __shfl_xor(rs, 32);
      lrun[qi] = lrun[qi]*alpha + rs;

      /* rescale O: alpha for O-row hi*4+r comes from lane la = hi*4+r */
      #pragma unroll
      for (int r = 0; r < 4; r++) {
        float ar = __shfl(alpha, (lane & 48) | ((hi << 2) | r), 64);
        #pragma unroll
        for (int df = 0; df < 8; df++) o[qi][df][r] *= ar;
      }

      /* pack P to bf16 pairs: c[mf][w] covers kv = mf*16+hi*4+2w+{0,1} */
      unsigned int c[4][2];
      #pragma unroll
      for (int mf = 0; mf < 4; mf++) {
        c[mf][0] = cvtpk_bf16(p[mf][0], p[mf][1]);
        c[mf][1] = cvtpk_bf16(p[mf][2], p[mf][3]);
      }
      /* assemble A-frag word w (kv = 32ks2+8hi+2w+{0,1}):
         from lane (la, 2(hi&1)+(w>>1)), reg c[2ks2+(hi>>1)][w&1] */
      #pragma unroll
      for (int ks2 = 0; ks2 < 2; ks2++) {
        #pragma unroll
        for (int w = 0; w < 4; w++) {
          int src = la + 16*(2*(hi & 1) + (w >> 1));
          unsigned int t0 = __shfl(c[2*ks2    ][w & 1], src, 64);
          unsigned int t1 = __shfl(c[2*ks2 + 1][w & 1], src, 64);
          pf[qi][ks2][w] = (hi >> 1) ? t1 : t0;
        }
      }
    }

    /* PV: O += P * V  (A = P rows, B = V^T rows) */
    #pragma unroll
    for (int ks2 = 0; ks2 < 2; ks2++) {
      #pragma unroll
      for (int df = 0; df < 8; df++) {
        int vrow = df*16 + la;
        int boff = ((vrow << 7) + (ks2 << 6) + (hi << 4)) ^ ((la & 7) << 4);
        bf16x8 vf = *(const bf16x8*)((const char*)VTs[cur] + boff);
        #pragma unroll
        for (int qi = 0; qi < 2; qi++) {
          u32x4 pw = {pf[qi][ks2][0], pf[qi][ks2][1], pf[qi][ks2][2], pf[qi][ks2][3]};
          o[qi][df] = __builtin_amdgcn_mfma_f32_16x16x32_bf16(
              __builtin_bit_cast(bf16x8, pw), vf, o[qi][df], 0, 0, 0);
        }
      }
    }
    __syncthreads();   /* drains vmcnt (next tile staged); guards buf reuse */
  }

  /* epilogue: O[b][s][h*128+d] bf16; 1/l for O-row hi*4+r from lane la=hi*4+r */
  unsigned short* Ob = O + (size_t)b * SEQ * D_MODEL + h * DH;
  #pragma unroll
  for (int qi = 0; qi < 2; qi++) {
    float linv[4];
    #pragma unroll
    for (int r = 0; r < 4; r++)
      linv[r] = 1.0f / __shfl(lrun[qi], (lane & 48) | ((hi << 2) | r), 64);
    #pragma unroll
    for (int df = 0; df < 8; df++)
      #pragma unroll
      for (int r = 0; r < 4; r++) {
        int srow = qrow + qi*16 + hi*4 + r;
        Ob[(size_t)srow * D_MODEL + df*16 + la] = f2bf(o[qi][df][r] * linv[r]);
      }
  }
}

/* ---------------- launcher ---------------- */
extern "C" void kernel_launch(void* const* d_in, const int* in_sizes, int n_in,
                              void* d_out, int out_size, void* d_ws, size_t ws_size,
                              hipStream_t stream) {
  const float* x  = (const float*)d_in[0];
  const float* wq = (const float*)d_in[1];
  const float* bq = (const float*)d_in[2];
  const float* wk = (const float*)d_in[3];
  const float* bk = (const float*)d_in[4];
  const float* wv = (const float*)d_in[5];
  const float* bv = (const float*)d_in[6];
  const float* wo = (const float*)d_in[7];
  const float* bo = (const float*)d_in[8];
  float* out = (float*)d_out;

  const size_t X = (size_t)MROWS * D_MODEL;   /* 8388608  */
  const size_t W = (size_t)D_MODEL * D_MODEL; /* 4194304  */

  unsigned short* ws  = (unsigned short*)d_ws;
  unsigned short* xb  = ws;
  unsigned short* wqb = xb  + X;
  unsigned short* wkb = wqb + W;
  unsigned short* wvb = wkb + W;
  unsigned short* wob = wvb + W;
  unsigned short* qb  = wob + W;
  unsigned short* kb  = qb  + X;
  unsigned short* vb  = kb  + X;
  unsigned short* ab  = vb  + X;
  unsigned short* vtg = xb;   /* alias: xb dead after QKV GEMMs */

  cast_f32_bf16<<<dim3((unsigned)(X/2048)), 256, 0, stream>>>(x,  xb);
  cast_f32_bf16<<<dim3((unsigned)(W/2048)), 256, 0, stream>>>(wq, wqb);
  cast_f32_bf16<<<dim3((unsigned)(W/2048)), 256, 0, stream>>>(wk, wkb);
  cast_f32_bf16<<<dim3((unsigned)(W/2048)), 256, 0, stream>>>(wv, wvb);
  cast_f32_bf16<<<dim3((unsigned)(W/2048)), 256, 0, stream>>>(wo, wob);

  dim3 ggrid(D_MODEL/128, MROWS/128);  /* 16 x 32 */
  gemm_bt<<<ggrid, 256, 0, stream>>>(xb, wqb, bq, qb, nullptr, 0);
  gemm_bt<<<ggrid, 256, 0, stream>>>(xb, wkb, bk, kb, nullptr, 2);
  gemm_bt<<<ggrid, 256, 0, stream>>>(xb, wvb, bv, vb, nullptr, 0);

  transpose_v<<<dim3(SEQ/64, NB*NH), 256, 0, stream>>>(vb, vtg);

  attn_fwd<<<dim3(512), 256, 0, stream>>>(qb, kb, vtg, ab);

  gemm_bt<<<ggrid, 256, 0, stream>>>(ab, wob, bo, nullptr, out, 1);
}

// Round 5
// 302.396 us; speedup vs baseline: 2.8893x; 1.1420x over previous
//
#include <hip/hip_runtime.h>

#define D_MODEL 2048
#define SEQ     2048
#define NB      2
#define NH      16
#define DH      128
#define MROWS   (NB*SEQ)   /* 4096 */
#define GK      2048       /* K dim of all GEMMs */
#define NT      (GK/64)    /* 32 K-tiles */

typedef __bf16 bf16x8 __attribute__((ext_vector_type(8)));
typedef float  f32x4  __attribute__((ext_vector_type(4)));
typedef unsigned short ushort8 __attribute__((ext_vector_type(8)));
typedef unsigned int   u32x4   __attribute__((ext_vector_type(4)));

__device__ __forceinline__ unsigned short f2bf(float f) {
  unsigned int u = __float_as_uint(f);
  u += 0x7FFFu + ((u >> 16) & 1u);
  return (unsigned short)(u >> 16);
}

__device__ __forceinline__ unsigned int cvtpk_bf16(float lo, float hi) {
  unsigned int r;
  asm("v_cvt_pk_bf16_f32 %0, %1, %2" : "=v"(r) : "v"(lo), "v"(hi));
  return r;
}

__device__ __forceinline__ void gload16(void* lds, const void* g) {
  __builtin_amdgcn_global_load_lds(
      (__attribute__((address_space(1))) void*)(g),
      (__attribute__((address_space(3))) void*)(lds), 16, 0, 0);
}

/* ---------------- fp32 -> bf16 cast, 8 elems/thread ---------------- */
__global__ __launch_bounds__(256) void cast_f32_bf16(
    const float* __restrict__ in, unsigned short* __restrict__ out) {
  int i = blockIdx.x * 256 + threadIdx.x;
  const float4* p = (const float4*)in;
  float4 a = p[2*i], b = p[2*i+1];
  ushort8 o;
  o[0]=f2bf(a.x); o[1]=f2bf(a.y); o[2]=f2bf(a.z); o[3]=f2bf(a.w);
  o[4]=f2bf(b.x); o[5]=f2bf(b.y); o[6]=f2bf(b.z); o[7]=f2bf(b.w);
  ((ushort8*)out)[i] = o;
}

/* ---------------- GEMM 128x256, BK=64, 8 waves (2x4), triple-buffered LDS,
   counted vmcnt (T4), XOR-swizzled LDS via pre-swizzled gload source (T2),
   XCD-chunked block swizzle (T1).
   C[M,N] = A[M,K] * B[N,K]^T + bias.
   mode 0 (QKV fused, B rows 0..6143 = wq|wk|wv):
     cols 0-2047   -> q head-major [b,h,s,d]
     cols 2048-4095-> k blocked+swizzled tiles
     cols 4096-6143-> v^T blocked+swizzled tiles
   mode 1: fp32 [M,2048] + bias.                                            */
__global__ __launch_bounds__(512, 2) void gemm256(
    const unsigned short* __restrict__ A,
    const unsigned short* __restrict__ B,
    const float* __restrict__ b0, const float* __restrict__ b1,
    const float* __restrict__ b2,
    unsigned short* __restrict__ qo, unsigned short* __restrict__ ko,
    unsigned short* __restrict__ vo, float* __restrict__ fo,
    int mode, int nblk)
{
  __shared__ char lds[3*49152];   /* per slot: A 16KB (128x64), B 32KB (256x64) */

  const int tid  = threadIdx.x;
  const int lane = tid & 63, wid = tid >> 6;
  const int la   = lane & 15, hi = lane >> 4;
  const int wm   = wid >> 2,  wn = wid & 3;

  const int linear = ((int)(blockIdx.x & 7)) * (nblk >> 3) + ((int)blockIdx.x >> 3);
  const int bm = linear & 31, bn = linear >> 5;

  const unsigned short* Ab = A + (size_t)(bm*128) * GK;
  const unsigned short* Bb = B + (size_t)(bn*256) * GK;

  f32x4 acc[4][4];
  #pragma unroll
  for (int m = 0; m < 4; m++)
    #pragma unroll
    for (int n = 0; n < 4; n++) acc[m][n] = f32x4{0.f,0.f,0.f,0.f};

#define STAGE(slot, kt) do {                                                  \
    int sb_ = (slot) * 49152;                                                 \
    _Pragma("unroll")                                                         \
    for (int j = 0; j < 2; j++) {                                             \
      int idx = j*512 + tid;                                                  \
      int row = idx >> 3;                                                     \
      int c   = (idx & 7) << 4;                                               \
      gload16(lds + sb_ + idx*16,                                             \
              Ab + (size_t)row*GK + (kt)*64 + ((c ^ ((row&7)<<4)) >> 1));     \
    }                                                                         \
    _Pragma("unroll")                                                         \
    for (int j = 0; j < 4; j++) {                                             \
      int idx = j*512 + tid;                                                  \
      int row = idx >> 3;                                                     \
      int c   = (idx & 7) << 4;                                               \
      gload16(lds + sb_ + 16384 + idx*16,                                     \
              Bb + (size_t)row*GK + (kt)*64 + ((c ^ ((row&7)<<4)) >> 1));     \
    }                                                                         \
  } while (0)

  STAGE(0, 0);
  STAGE(1, 1);

  int cs = 0, ps = 2;
  const int xr = (la & 7) << 4;

  #pragma unroll 1
  for (int t = 0; t < NT; ++t) {
    if (t + 2 < NT) STAGE(ps, t + 2);

    /* wait for tile t: tiles beyond t still outstanding = 6 loads each */
    if (t + 2 < NT)      asm volatile("s_waitcnt vmcnt(12)" ::: "memory");
    else if (t + 1 < NT) asm volatile("s_waitcnt vmcnt(6)"  ::: "memory");
    else                 asm volatile("s_waitcnt vmcnt(0)"  ::: "memory");
    __builtin_amdgcn_s_barrier();
    asm volatile("" ::: "memory");

    const char* sa = lds + cs*49152;
    const char* sb = sa + 16384;
    #pragma unroll
    for (int ks = 0; ks < 2; ks++) {
      bf16x8 a[4], b[4];
      #pragma unroll
      for (int m = 0; m < 4; m++)
        a[m] = *(const bf16x8*)(sa + (((wm*64 + m*16 + la)*128 + ks*64 + hi*16) ^ xr));
      #pragma unroll
      for (int n = 0; n < 4; n++)
        b[n] = *(const bf16x8*)(sb + (((wn*64 + n*16 + la)*128 + ks*64 + hi*16) ^ xr));
      #pragma unroll
      for (int m = 0; m < 4; m++)
        #pragma unroll
        for (int n = 0; n < 4; n++)
          acc[m][n] = __builtin_amdgcn_mfma_f32_16x16x32_bf16(a[m], b[n], acc[m][n], 0, 0, 0);
    }
    asm volatile("" ::: "memory");
    __builtin_amdgcn_s_barrier();   /* all waves done reading slot cs before it is restaged */

    cs = cs + 1; if (cs == 3) cs = 0;
    ps = ps + 1; if (ps == 3) ps = 0;
  }
#undef STAGE

  /* epilogue */
  const int row0 = bm*128 + wm*64;
  const int col0 = bn*256 + wn*64;

  if (mode == 1) {
    #pragma unroll
    for (int n = 0; n < 4; n++) {
      int col = col0 + n*16 + la;
      float bv = b0[col];
      #pragma unroll
      for (int m = 0; m < 4; m++)
        #pragma unroll
        for (int r = 0; r < 4; r++) {
          int row = row0 + m*16 + hi*4 + r;
          fo[(size_t)row*D_MODEL + col] = acc[m][n][r] + bv;
        }
    }
  } else {
    const int mat = col0 >> 11;   /* uniform per block: 0=q 1=k 2=v */
    const float* bp = (mat == 0) ? b0 : (mat == 1) ? b1 : b2;
    #pragma unroll
    for (int n = 0; n < 4; n++) {
      int col = col0 + n*16 + la;
      int c   = col & 2047;
      int h   = c >> 7, d = c & 127;
      float bv = bp[c];
      #pragma unroll
      for (int m = 0; m < 4; m++)
        #pragma unroll
        for (int r = 0; r < 4; r++) {
          int row = row0 + m*16 + hi*4 + r;
          int b   = row >> 11, s = row & (SEQ-1);
          unsigned short val = f2bf(acc[m][n][r] + bv);
          if (mat == 0) {
            qo[((size_t)(b*NH + h)*SEQ + s)*DH + d] = val;
          } else if (mat == 1) {
            size_t base = ((size_t)(b*NH + h)*SEQ + (size_t)(s >> 6)*64)*DH;
            int boff = (((s & 63) << 8) + (d << 1)) ^ ((s & 7) << 4);
            ko[base + (boff >> 1)] = val;
          } else {
            size_t base = ((size_t)(b*NH + h)*SEQ + (size_t)(s >> 6)*64)*DH;
            int boff = ((d << 7) + ((s & 63) << 1)) ^ ((d & 7) << 4);
            vo[base + (boff >> 1)] = val;
          }
        }
    }
  }
}

/* ---------------- flash attention fwd ----------------
   512 blocks XCD-swizzled (4 bh per XCD -> K/V L2-resident).
   4 waves x 32 q-rows, KV tile 64, double-buffered K/V LDS (64KB).
   Swapped QK^T (S^T = mfma(K,Q)) -> softmax fully in-register,
   P assembled to PV A-frags via cvt_pk_bf16 + shfl.                       */
__global__ __launch_bounds__(256, 2) void attn_fwd(
    const unsigned short* __restrict__ Q,
    const unsigned short* __restrict__ Kg,
    const unsigned short* __restrict__ VTg,
    unsigned short* __restrict__ O)
{
  __shared__ unsigned short Ks [2][64*128];
  __shared__ unsigned short VTs[2][128*64];

  const int tid  = threadIdx.x;
  const int lane = tid & 63, wid = tid >> 6;
  const int la   = lane & 15, hi = lane >> 4;
  const int swz  = ((int)(blockIdx.x & 7) << 6) + ((int)blockIdx.x >> 3);
  const int bh   = swz >> 4;
  const int q0   = (swz & 15) << 7;
  const int b    = bh >> 4, h = bh & 15;

  const unsigned short* Qh = Q   + (size_t)bh * SEQ * DH;
  const unsigned short* Kh = Kg  + (size_t)bh * SEQ * DH;
  const unsigned short* Vh = VTg + (size_t)bh * SEQ * DH;

  const int qrow = q0 + wid * 32;

  bf16x8 qf[2][4];
  #pragma unroll
  for (int qi = 0; qi < 2; qi++)
    #pragma unroll
    for (int ks = 0; ks < 4; ks++)
      qf[qi][ks] = *(const bf16x8*)(Qh + (size_t)(qrow + qi*16 + la)*DH + ks*32 + hi*8);

  f32x4 o[2][8];
  float mrun[2], lrun[2];
  #pragma unroll
  for (int qi = 0; qi < 2; qi++) {
    #pragma unroll
    for (int df = 0; df < 8; df++) o[qi][df] = f32x4{0.f,0.f,0.f,0.f};
    mrun[qi] = -1e30f; lrun[qi] = 0.f;
  }

  #pragma unroll
  for (int i = 0; i < 4; i++) {
    int off = i*4096 + tid*16;
    gload16((char*)Ks[0]  + off, (const char*)Kh + off);
    gload16((char*)VTs[0] + off, (const char*)Vh + off);
  }
  __syncthreads();

  const float sc = 0.08838834764831845f; /* 1/sqrt(128) */

  #pragma unroll 1
  for (int t = 0; t < SEQ/64; ++t) {
    const int cur = t & 1;

    if (t + 1 < SEQ/64) {
      const char* kt = (const char*)(Kh + (size_t)(t+1)*(64*DH));
      const char* vt = (const char*)(Vh + (size_t)(t+1)*(64*DH));
      #pragma unroll
      for (int i = 0; i < 4; i++) {
        int off = i*4096 + tid*16;
        gload16((char*)Ks[cur^1]  + off, kt + off);
        gload16((char*)VTs[cur^1] + off, vt + off);
      }
    }

    /* S^T[kv][q] = K Q^T : S[mf][qi], kv = mf*16+hi*4+r, q = qi*16+la */
    f32x4 S[4][2];
    #pragma unroll
    for (int mf = 0; mf < 4; mf++)
      #pragma unroll
      for (int qi = 0; qi < 2; qi++) S[mf][qi] = f32x4{0.f,0.f,0.f,0.f};
    #pragma unroll
    for (int ks = 0; ks < 4; ks++) {
      bf16x8 kf[4];
      #pragma unroll
      for (int mf = 0; mf < 4; mf++) {
        int boff = (((mf*16 + la) << 8) + (ks << 6) + (hi << 4)) ^ ((la & 7) << 4);
        kf[mf] = *(const bf16x8*)((const char*)Ks[cur] + boff);
      }
      #pragma unroll
      for (int mf = 0; mf < 4; mf++)
        #pragma unroll
        for (int qi = 0; qi < 2; qi++)
          S[mf][qi] = __builtin_amdgcn_mfma_f32_16x16x32_bf16(kf[mf], qf[qi][ks], S[mf][qi], 0, 0, 0);
    }

    unsigned int pf[2][2][4];
    #pragma unroll
    for (int qi = 0; qi < 2; qi++) {
      float pm = S[0][qi][0];
      #pragma unroll
      for (int mf = 0; mf < 4; mf++)
        #pragma unroll
        for (int r = 0; r < 4; r++) pm = fmaxf(pm, S[mf][qi][r]);
      pm = fmaxf(pm, __shfl_xor(pm, 16));
      pm = fmaxf(pm, __shfl_xor(pm, 32));
      pm *= sc;
      float mn    = fmaxf(mrun[qi], pm);
      float alpha = __expf(mrun[qi] - mn);
      mrun[qi] = mn;

      float p[4][4]; float rs = 0.f;
      #pragma unroll
      for (int mf = 0; mf < 4; mf++)
        #pragma unroll
        for (int r = 0; r < 4; r++) {
          float e = __expf(fmaf(S[mf][qi][r], sc, -mn));
          p[mf][r] = e; rs += e;
        }
      rs += __shfl_xor(rs, 16);
      rs += __shfl_xor(rs, 32);
      lrun[qi] = lrun[qi]*alpha + rs;

      #pragma unroll
      for (int r = 0; r < 4; r++) {
        float ar = __shfl(alpha, (lane & 48) | ((hi << 2) | r), 64);
        #pragma unroll
        for (int df = 0; df < 8; df++) o[qi][df][r] *= ar;
      }

      unsigned int c[4][2];
      #pragma unroll
      for (int mf = 0; mf < 4; mf++) {
        c[mf][0] = cvtpk_bf16(p[mf][0], p[mf][1]);
        c[mf][1] = cvtpk_bf16(p[mf][2], p[mf][3]);
      }
      #pragma unroll
      for (int ks2 = 0; ks2 < 2; ks2++) {
        #pragma unroll
        for (int w = 0; w < 4; w++) {
          int src = la + 16*(2*(hi & 1) + (w >> 1));
          unsigned int t0 = __shfl(c[2*ks2    ][w & 1], src, 64);
          unsigned int t1 = __shfl(c[2*ks2 + 1][w & 1], src, 64);
          pf[qi][ks2][w] = (hi >> 1) ? t1 : t0;
        }
      }
    }

    #pragma unroll
    for (int ks2 = 0; ks2 < 2; ks2++) {
      #pragma unroll
      for (int df = 0; df < 8; df++) {
        int vrow = df*16 + la;
        int boff = ((vrow << 7) + (ks2 << 6) + (hi << 4)) ^ ((la & 7) << 4);
        bf16x8 vf = *(const bf16x8*)((const char*)VTs[cur] + boff);
        #pragma unroll
        for (int qi = 0; qi < 2; qi++) {
          u32x4 pw = {pf[qi][ks2][0], pf[qi][ks2][1], pf[qi][ks2][2], pf[qi][ks2][3]};
          o[qi][df] = __builtin_amdgcn_mfma_f32_16x16x32_bf16(
              __builtin_bit_cast(bf16x8, pw), vf, o[qi][df], 0, 0, 0);
        }
      }
    }
    __syncthreads();
  }

  unsigned short* Ob = O + (size_t)b * SEQ * D_MODEL + h * DH;
  #pragma unroll
  for (int qi = 0; qi < 2; qi++) {
    float linv[4];
    #pragma unroll
    for (int r = 0; r < 4; r++)
      linv[r] = 1.0f / __shfl(lrun[qi], (lane & 48) | ((hi << 2) | r), 64);
    #pragma unroll
    for (int df = 0; df < 8; df++)
      #pragma unroll
      for (int r = 0; r < 4; r++) {
        int srow = qrow + qi*16 + hi*4 + r;
        Ob[(size_t)srow * D_MODEL + df*16 + la] = f2bf(o[qi][df][r] * linv[r]);
      }
  }
}

/* ---------------- launcher ---------------- */
extern "C" void kernel_launch(void* const* d_in, const int* in_sizes, int n_in,
                              void* d_out, int out_size, void* d_ws, size_t ws_size,
                              hipStream_t stream) {
  const float* x  = (const float*)d_in[0];
  const float* wq = (const float*)d_in[1];
  const float* bq = (const float*)d_in[2];
  const float* wk = (const float*)d_in[3];
  const float* bk = (const float*)d_in[4];
  const float* wv = (const float*)d_in[5];
  const float* bv = (const float*)d_in[6];
  const float* wo = (const float*)d_in[7];
  const float* bo = (const float*)d_in[8];
  float* out = (float*)d_out;

  const size_t X = (size_t)MROWS * D_MODEL;   /* 8388608  */
  const size_t W = (size_t)D_MODEL * D_MODEL; /* 4194304  */

  unsigned short* ws  = (unsigned short*)d_ws;
  unsigned short* xb  = ws;
  unsigned short* wqb = xb  + X;   /* wqb,wkb,wvb contiguous = B[6144][2048] */
  unsigned short* wkb = wqb + W;
  unsigned short* wvb = wkb + W;
  unsigned short* wob = wvb + W;
  unsigned short* qb  = wob + W;
  unsigned short* kb  = qb  + X;
  unsigned short* vtg = kb  + X;
  unsigned short* ab  = vtg + X;

  cast_f32_bf16<<<dim3((unsigned)(X/2048)), 256, 0, stream>>>(x,  xb);
  cast_f32_bf16<<<dim3((unsigned)(W/2048)), 256, 0, stream>>>(wq, wqb);
  cast_f32_bf16<<<dim3((unsigned)(W/2048)), 256, 0, stream>>>(wk, wkb);
  cast_f32_bf16<<<dim3((unsigned)(W/2048)), 256, 0, stream>>>(wv, wvb);
  cast_f32_bf16<<<dim3((unsigned)(W/2048)), 256, 0, stream>>>(wo, wob);

  /* fused QKV: M=4096, N=6144 -> 32x24 = 768 blocks (3 exact CU-rounds) */
  gemm256<<<dim3(768), 512, 0, stream>>>(xb, wqb, bq, bk, bv,
                                         qb, kb, vtg, nullptr, 0, 768);

  attn_fwd<<<dim3(512), 256, 0, stream>>>(qb, kb, vtg, ab);

  /* out-proj: M=4096, N=2048 -> 32x8 = 256 blocks (1 exact CU-round) */
  gemm256<<<dim3(256), 512, 0, stream>>>(ab, wob, bo, bo, bo,
                                         nullptr, nullptr, nullptr, out, 1, 256);
}

// Round 6
// 301.063 us; speedup vs baseline: 2.9020x; 1.0044x over previous
//
#include <hip/hip_runtime.h>

#define D_MODEL 2048
#define SEQ     2048
#define NB      2
#define NH      16
#define DH      128
#define MROWS   (NB*SEQ)   /* 4096 */
#define GK      2048       /* K dim of all GEMMs */
#define NT      (GK/64)    /* 32 K-tiles */

typedef __bf16 bf16x8 __attribute__((ext_vector_type(8)));
typedef float  f32x4  __attribute__((ext_vector_type(4)));
typedef unsigned short ushort8 __attribute__((ext_vector_type(8)));
typedef unsigned int   u32x4   __attribute__((ext_vector_type(4)));

__device__ __forceinline__ unsigned short f2bf(float f) {
  unsigned int u = __float_as_uint(f);
  u += 0x7FFFu + ((u >> 16) & 1u);
  return (unsigned short)(u >> 16);
}

__device__ __forceinline__ unsigned int cvtpk_bf16(float lo, float hi) {
  unsigned int r;
  asm("v_cvt_pk_bf16_f32 %0, %1, %2" : "=v"(r) : "v"(lo), "v"(hi));
  return r;
}

__device__ __forceinline__ void gload16(void* lds, const void* g) {
  __builtin_amdgcn_global_load_lds(
      (__attribute__((address_space(1))) void*)(g),
      (__attribute__((address_space(3))) void*)(lds), 16, 0, 0);
}

/* ---------------- fp32 -> bf16 cast, 8 elems/thread ---------------- */
__global__ __launch_bounds__(256) void cast_f32_bf16(
    const float* __restrict__ in, unsigned short* __restrict__ out) {
  int i = blockIdx.x * 256 + threadIdx.x;
  const float4* p = (const float4*)in;
  float4 a = p[2*i], b = p[2*i+1];
  ushort8 o;
  o[0]=f2bf(a.x); o[1]=f2bf(a.y); o[2]=f2bf(a.z); o[3]=f2bf(a.w);
  o[4]=f2bf(b.x); o[5]=f2bf(b.y); o[6]=f2bf(b.z); o[7]=f2bf(b.w);
  ((ushort8*)out)[i] = o;
}

/* ---------------- GEMM 128x256, BK=64, 8 waves (2x4), triple-buffered LDS,
   phased schedule (T3-style): per K-tile 2 phases, each {ds_read frag set ∥
   stage part of tile t+2, lgkmcnt(0), setprio(1)+16 MFMA}; counted vmcnt(6)
   + raw barrier at iter top (T4); zero-conflict XOR swizzle via pre-swizzled
   gload source (T2); XCD-chunked block swizzle (T1).
   C[M,N] = A[M,K] * B[N,K]^T + bias.
   mode 0 (QKV fused, B rows = wq|wk|wv): q head-major / k swz / v^T swz.
   mode 1: fp32 [M,2048] + bias.                                            */
__global__ __launch_bounds__(512, 2) void gemm256(
    const unsigned short* __restrict__ A,
    const unsigned short* __restrict__ B,
    const float* __restrict__ b0, const float* __restrict__ b1,
    const float* __restrict__ b2,
    unsigned short* __restrict__ qo, unsigned short* __restrict__ ko,
    unsigned short* __restrict__ vo, float* __restrict__ fo,
    int mode, int nblk)
{
  __shared__ char lds[3*49152];   /* per slot: A 16KB (128x64), B 32KB (256x64) */

  const int tid  = threadIdx.x;
  const int lane = tid & 63, wid = tid >> 6;
  const int la   = lane & 15, hi = lane >> 4;
  const int wm   = wid >> 2,  wn = wid & 3;

  const int linear = ((int)(blockIdx.x & 7)) * (nblk >> 3) + ((int)blockIdx.x >> 3);
  const int bm = linear & 31, bn = linear >> 5;

  const unsigned short* Ab = A + (size_t)(bm*128) * GK;
  const unsigned short* Bb = B + (size_t)(bn*256) * GK;

  f32x4 acc[4][4];
  #pragma unroll
  for (int m = 0; m < 4; m++)
    #pragma unroll
    for (int n = 0; n < 4; n++) acc[m][n] = f32x4{0.f,0.f,0.f,0.f};

#define STAGE_A(slot, kt) do {                                                \
    int sb_ = (slot) * 49152;                                                 \
    _Pragma("unroll")                                                         \
    for (int j = 0; j < 2; j++) {                                             \
      int idx = j*512 + tid;                                                  \
      int row = idx >> 3;                                                     \
      int c   = (idx & 7) << 4;                                               \
      gload16(lds + sb_ + idx*16,                                             \
              Ab + (size_t)row*GK + (kt)*64 + ((c ^ ((row&7)<<4)) >> 1));     \
    }                                                                         \
  } while (0)

#define STAGE_B(slot, kt) do {                                                \
    int sb_ = (slot) * 49152;                                                 \
    _Pragma("unroll")                                                         \
    for (int j = 0; j < 4; j++) {                                             \
      int idx = j*512 + tid;                                                  \
      int row = idx >> 3;                                                     \
      int c   = (idx & 7) << 4;                                               \
      gload16(lds + sb_ + 16384 + idx*16,                                     \
              Bb + (size_t)row*GK + (kt)*64 + ((c ^ ((row&7)<<4)) >> 1));     \
    }                                                                         \
  } while (0)

  STAGE_A(0, 0); STAGE_B(0, 0);
  STAGE_A(1, 1); STAGE_B(1, 1);

  int cs = 0, ps = 2;
  const int xr = (la & 7) << 4;

  #pragma unroll 1
  for (int t = 0; t < NT; ++t) {
    /* availability wait for tile t (staged at iter t-2): outstanding = tile
       t+1's 6 loads if it exists; never drain to 0 mid-loop (T4). */
    if (t + 1 < NT) asm volatile("s_waitcnt vmcnt(6)" ::: "memory");
    else            asm volatile("s_waitcnt vmcnt(0)" ::: "memory");
    __builtin_amdgcn_s_barrier();        /* tile t visible to all waves */

    const char* sa  = lds + cs*49152;
    const char* sbp = sa + 16384;

    /* ---- phase A: B-frags + A rows 0-1; stage A-part of t+2; MFMA m0-1 */
    bf16x8 bfr[4][2], aA[2][2];
    #pragma unroll
    for (int n = 0; n < 4; n++)
      #pragma unroll
      for (int ks = 0; ks < 2; ks++)
        bfr[n][ks] = *(const bf16x8*)(sbp + (((wn*64 + n*16 + la)*128 + ks*64 + hi*16) ^ xr));
    #pragma unroll
    for (int m = 0; m < 2; m++)
      #pragma unroll
      for (int ks = 0; ks < 2; ks++)
        aA[m][ks] = *(const bf16x8*)(sa + (((wm*64 + m*16 + la)*128 + ks*64 + hi*16) ^ xr));

    if (t + 2 < NT) STAGE_A(ps, t + 2);

    asm volatile("s_waitcnt lgkmcnt(0)" ::: "memory");
    __builtin_amdgcn_sched_barrier(0);
    __builtin_amdgcn_s_setprio(1);
    #pragma unroll
    for (int m = 0; m < 2; m++)
      #pragma unroll
      for (int n = 0; n < 4; n++)
        #pragma unroll
        for (int ks = 0; ks < 2; ks++)
          acc[m][n] = __builtin_amdgcn_mfma_f32_16x16x32_bf16(aA[m][ks], bfr[n][ks], acc[m][n], 0, 0, 0);
    __builtin_amdgcn_s_setprio(0);
    __builtin_amdgcn_s_barrier();        /* phase-lock */

    /* ---- phase B: A rows 2-3; stage B-part of t+2; MFMA m2-3 */
    bf16x8 aB[2][2];
    #pragma unroll
    for (int m = 0; m < 2; m++)
      #pragma unroll
      for (int ks = 0; ks < 2; ks++)
        aB[m][ks] = *(const bf16x8*)(sa + (((wm*64 + (m+2)*16 + la)*128 + ks*64 + hi*16) ^ xr));

    if (t + 2 < NT) STAGE_B(ps, t + 2);

    asm volatile("s_waitcnt lgkmcnt(0)" ::: "memory");
    __builtin_amdgcn_sched_barrier(0);
    __builtin_amdgcn_s_setprio(1);
    #pragma unroll
    for (int m = 0; m < 2; m++)
      #pragma unroll
      for (int n = 0; n < 4; n++)
        #pragma unroll
        for (int ks = 0; ks < 2; ks++)
          acc[m+2][n] = __builtin_amdgcn_mfma_f32_16x16x32_bf16(aB[m][ks], bfr[n][ks], acc[m+2][n], 0, 0, 0);
    __builtin_amdgcn_s_setprio(0);

    cs = cs + 1; if (cs == 3) cs = 0;
    ps = ps + 1; if (ps == 3) ps = 0;
  }
#undef STAGE_A
#undef STAGE_B

  /* epilogue */
  const int row0 = bm*128 + wm*64;
  const int col0 = bn*256 + wn*64;

  if (mode == 1) {
    #pragma unroll
    for (int n = 0; n < 4; n++) {
      int col = col0 + n*16 + la;
      float bv = b0[col];
      #pragma unroll
      for (int m = 0; m < 4; m++)
        #pragma unroll
        for (int r = 0; r < 4; r++) {
          int row = row0 + m*16 + hi*4 + r;
          fo[(size_t)row*D_MODEL + col] = acc[m][n][r] + bv;
        }
    }
  } else {
    const int mat = col0 >> 11;   /* uniform per block: 0=q 1=k 2=v */
    const float* bp = (mat == 0) ? b0 : (mat == 1) ? b1 : b2;
    #pragma unroll
    for (int n = 0; n < 4; n++) {
      int col = col0 + n*16 + la;
      int c   = col & 2047;
      int h   = c >> 7, d = c & 127;
      float bv = bp[c];
      #pragma unroll
      for (int m = 0; m < 4; m++)
        #pragma unroll
        for (int r = 0; r < 4; r++) {
          int row = row0 + m*16 + hi*4 + r;
          int b   = row >> 11, s = row & (SEQ-1);
          unsigned short val = f2bf(acc[m][n][r] + bv);
          if (mat == 0) {
            qo[((size_t)(b*NH + h)*SEQ + s)*DH + d] = val;
          } else if (mat == 1) {
            size_t base = ((size_t)(b*NH + h)*SEQ + (size_t)(s >> 6)*64)*DH;
            int boff = (((s & 63) << 8) + (d << 1)) ^ ((s & 7) << 4);
            ko[base + (boff >> 1)] = val;
          } else {
            size_t base = ((size_t)(b*NH + h)*SEQ + (size_t)(s >> 6)*64)*DH;
            int boff = ((d << 7) + ((s & 63) << 1)) ^ ((d & 7) << 4);
            vo[base + (boff >> 1)] = val;
          }
        }
    }
  }
}

/* ---------------- flash attention fwd ----------------
   512 blocks XCD-swizzled (4 bh per XCD -> K/V L2-resident).
   4 waves x 32 q-rows, KV tile 64, double-buffered K/V LDS (64KB).
   Swapped QK^T (S^T = mfma(K,Q)) -> softmax fully in-register,
   P assembled to PV A-frags via cvt_pk_bf16 + shfl.                       */
__global__ __launch_bounds__(256, 2) void attn_fwd(
    const unsigned short* __restrict__ Q,
    const unsigned short* __restrict__ Kg,
    const unsigned short* __restrict__ VTg,
    unsigned short* __restrict__ O)
{
  __shared__ unsigned short Ks [2][64*128];
  __shared__ unsigned short VTs[2][128*64];

  const int tid  = threadIdx.x;
  const int lane = tid & 63, wid = tid >> 6;
  const int la   = lane & 15, hi = lane >> 4;
  const int swz  = ((int)(blockIdx.x & 7) << 6) + ((int)blockIdx.x >> 3);
  const int bh   = swz >> 4;
  const int q0   = (swz & 15) << 7;
  const int b    = bh >> 4, h = bh & 15;

  const unsigned short* Qh = Q   + (size_t)bh * SEQ * DH;
  const unsigned short* Kh = Kg  + (size_t)bh * SEQ * DH;
  const unsigned short* Vh = VTg + (size_t)bh * SEQ * DH;

  const int qrow = q0 + wid * 32;

  bf16x8 qf[2][4];
  #pragma unroll
  for (int qi = 0; qi < 2; qi++)
    #pragma unroll
    for (int ks = 0; ks < 4; ks++)
      qf[qi][ks] = *(const bf16x8*)(Qh + (size_t)(qrow + qi*16 + la)*DH + ks*32 + hi*8);

  f32x4 o[2][8];
  float mrun[2], lrun[2];
  #pragma unroll
  for (int qi = 0; qi < 2; qi++) {
    #pragma unroll
    for (int df = 0; df < 8; df++) o[qi][df] = f32x4{0.f,0.f,0.f,0.f};
    mrun[qi] = -1e30f; lrun[qi] = 0.f;
  }

  #pragma unroll
  for (int i = 0; i < 4; i++) {
    int off = i*4096 + tid*16;
    gload16((char*)Ks[0]  + off, (const char*)Kh + off);
    gload16((char*)VTs[0] + off, (const char*)Vh + off);
  }
  __syncthreads();

  const float sc = 0.08838834764831845f; /* 1/sqrt(128) */

  #pragma unroll 1
  for (int t = 0; t < SEQ/64; ++t) {
    const int cur = t & 1;

    if (t + 1 < SEQ/64) {
      const char* kt = (const char*)(Kh + (size_t)(t+1)*(64*DH));
      const char* vt = (const char*)(Vh + (size_t)(t+1)*(64*DH));
      #pragma unroll
      for (int i = 0; i < 4; i++) {
        int off = i*4096 + tid*16;
        gload16((char*)Ks[cur^1]  + off, kt + off);
        gload16((char*)VTs[cur^1] + off, vt + off);
      }
    }

    /* S^T[kv][q] = K Q^T : S[mf][qi], kv = mf*16+hi*4+r, q = qi*16+la */
    f32x4 S[4][2];
    #pragma unroll
    for (int mf = 0; mf < 4; mf++)
      #pragma unroll
      for (int qi = 0; qi < 2; qi++) S[mf][qi] = f32x4{0.f,0.f,0.f,0.f};
    #pragma unroll
    for (int ks = 0; ks < 4; ks++) {
      bf16x8 kf[4];
      #pragma unroll
      for (int mf = 0; mf < 4; mf++) {
        int boff = (((mf*16 + la) << 8) + (ks << 6) + (hi << 4)) ^ ((la & 7) << 4);
        kf[mf] = *(const bf16x8*)((const char*)Ks[cur] + boff);
      }
      #pragma unroll
      for (int mf = 0; mf < 4; mf++)
        #pragma unroll
        for (int qi = 0; qi < 2; qi++)
          S[mf][qi] = __builtin_amdgcn_mfma_f32_16x16x32_bf16(kf[mf], qf[qi][ks], S[mf][qi], 0, 0, 0);
    }

    unsigned int pf[2][2][4];
    #pragma unroll
    for (int qi = 0; qi < 2; qi++) {
      float pm = S[0][qi][0];
      #pragma unroll
      for (int mf = 0; mf < 4; mf++)
        #pragma unroll
        for (int r = 0; r < 4; r++) pm = fmaxf(pm, S[mf][qi][r]);
      pm = fmaxf(pm, __shfl_xor(pm, 16));
      pm = fmaxf(pm, __shfl_xor(pm, 32));
      pm *= sc;
      float mn    = fmaxf(mrun[qi], pm);
      float alpha = __expf(mrun[qi] - mn);
      mrun[qi] = mn;

      float p[4][4]; float rs = 0.f;
      #pragma unroll
      for (int mf = 0; mf < 4; mf++)
        #pragma unroll
        for (int r = 0; r < 4; r++) {
          float e = __expf(fmaf(S[mf][qi][r], sc, -mn));
          p[mf][r] = e; rs += e;
        }
      rs += __shfl_xor(rs, 16);
      rs += __shfl_xor(rs, 32);
      lrun[qi] = lrun[qi]*alpha + rs;

      #pragma unroll
      for (int r = 0; r < 4; r++) {
        float ar = __shfl(alpha, (lane & 48) | ((hi << 2) | r), 64);
        #pragma unroll
        for (int df = 0; df < 8; df++) o[qi][df][r] *= ar;
      }

      unsigned int c[4][2];
      #pragma unroll
      for (int mf = 0; mf < 4; mf++) {
        c[mf][0] = cvtpk_bf16(p[mf][0], p[mf][1]);
        c[mf][1] = cvtpk_bf16(p[mf][2], p[mf][3]);
      }
      #pragma unroll
      for (int ks2 = 0; ks2 < 2; ks2++) {
        #pragma unroll
        for (int w = 0; w < 4; w++) {
          int src = la + 16*(2*(hi & 1) + (w >> 1));
          unsigned int t0 = __shfl(c[2*ks2    ][w & 1], src, 64);
          unsigned int t1 = __shfl(c[2*ks2 + 1][w & 1], src, 64);
          pf[qi][ks2][w] = (hi >> 1) ? t1 : t0;
        }
      }
    }

    #pragma unroll
    for (int ks2 = 0; ks2 < 2; ks2++) {
      #pragma unroll
      for (int df = 0; df < 8; df++) {
        int vrow = df*16 + la;
        int boff = ((vrow << 7) + (ks2 << 6) + (hi << 4)) ^ ((la & 7) << 4);
        bf16x8 vf = *(const bf16x8*)((const char*)VTs[cur] + boff);
        #pragma unroll
        for (int qi = 0; qi < 2; qi++) {
          u32x4 pw = {pf[qi][ks2][0], pf[qi][ks2][1], pf[qi][ks2][2], pf[qi][ks2][3]};
          o[qi][df] = __builtin_amdgcn_mfma_f32_16x16x32_bf16(
              __builtin_bit_cast(bf16x8, pw), vf, o[qi][df], 0, 0, 0);
        }
      }
    }
    __syncthreads();
  }

  unsigned short* Ob = O + (size_t)b * SEQ * D_MODEL + h * DH;
  #pragma unroll
  for (int qi = 0; qi < 2; qi++) {
    float linv[4];
    #pragma unroll
    for (int r = 0; r < 4; r++)
      linv[r] = 1.0f / __shfl(lrun[qi], (lane & 48) | ((hi << 2) | r), 64);
    #pragma unroll
    for (int df = 0; df < 8; df++)
      #pragma unroll
      for (int r = 0; r < 4; r++) {
        int srow = qrow + qi*16 + hi*4 + r;
        Ob[(size_t)srow * D_MODEL + df*16 + la] = f2bf(o[qi][df][r] * linv[r]);
      }
  }
}

/* ---------------- launcher ---------------- */
extern "C" void kernel_launch(void* const* d_in, const int* in_sizes, int n_in,
                              void* d_out, int out_size, void* d_ws, size_t ws_size,
                              hipStream_t stream) {
  const float* x  = (const float*)d_in[0];
  const float* wq = (const float*)d_in[1];
  const float* bq = (const float*)d_in[2];
  const float* wk = (const float*)d_in[3];
  const float* bk = (const float*)d_in[4];
  const float* wv = (const float*)d_in[5];
  const float* bv = (const float*)d_in[6];
  const float* wo = (const float*)d_in[7];
  const float* bo = (const float*)d_in[8];
  float* out = (float*)d_out;

  const size_t X = (size_t)MROWS * D_MODEL;   /* 8388608  */
  const size_t W = (size_t)D_MODEL * D_MODEL; /* 4194304  */

  unsigned short* ws  = (unsigned short*)d_ws;
  unsigned short* xb  = ws;
  unsigned short* wqb = xb  + X;   /* wqb,wkb,wvb contiguous = B[6144][2048] */
  unsigned short* wkb = wqb + W;
  unsigned short* wvb = wkb + W;
  unsigned short* wob = wvb + W;
  unsigned short* qb  = wob + W;
  unsigned short* kb  = qb  + X;
  unsigned short* vtg = kb  + X;
  unsigned short* ab  = vtg + X;

  cast_f32_bf16<<<dim3((unsigned)(X/2048)), 256, 0, stream>>>(x,  xb);
  cast_f32_bf16<<<dim3((unsigned)(W/2048)), 256, 0, stream>>>(wq, wqb);
  cast_f32_bf16<<<dim3((unsigned)(W/2048)), 256, 0, stream>>>(wk, wkb);
  cast_f32_bf16<<<dim3((unsigned)(W/2048)), 256, 0, stream>>>(wv, wvb);
  cast_f32_bf16<<<dim3((unsigned)(W/2048)), 256, 0, stream>>>(wo, wob);

  /* fused QKV: M=4096, N=6144 -> 32x24 = 768 blocks (3 exact CU-rounds) */
  gemm256<<<dim3(768), 512, 0, stream>>>(xb, wqb, bq, bk, bv,
                                         qb, kb, vtg, nullptr, 0, 768);

  attn_fwd<<<dim3(512), 256, 0, stream>>>(qb, kb, vtg, ab);

  /* out-proj: M=4096, N=2048 -> 32x8 = 256 blocks (1 exact CU-round) */
  gemm256<<<dim3(256), 512, 0, stream>>>(ab, wob, bo, bo, bo,
                                         nullptr, nullptr, nullptr, out, 1, 256);
}